// Round 1
// baseline (6679.720 us; speedup 1.0000x reference)
//
#include <hip/hip_runtime.h>
#include <hip/hip_bf16.h>

#define N_NODES 50000
#define N_EDGES 800000
#define DIN_    64
#define EIN_    16
#define H_      300
#define R_OUT   1024
#define G_GR    256
#define DEPTH_  5
#define KPAD    320
#define NPAD    50048   // multiple of 64 >= N_NODES

typedef unsigned short ushort_t;
typedef __attribute__((ext_vector_type(8))) short bf16x8;
typedef __attribute__((ext_vector_type(4))) float f32x4;

__device__ __forceinline__ ushort_t f2b(float f) {
  unsigned x = __float_as_uint(f);
  unsigned r = (x + 0x7fffu + ((x >> 16) & 1u)) >> 16;  // RTN-even
  return (ushort_t)r;
}

// Pack W1/W2 (fp32 [DEPTH][300][300], k-major) into bf16 frag layout
// Bp[i][kg][n][j] , k = kg*8+j, zero-padded to 320x320.
__global__ void pack_weights(const float* __restrict__ W1, const float* __restrict__ W2,
                             ushort_t* __restrict__ Bp1, ushort_t* __restrict__ Bp2) {
  int idx = blockIdx.x * 256 + threadIdx.x;
  const int per = DEPTH_ * 40 * KPAD * 8;  // 512000
  if (idx >= 2 * per) return;
  const float* W = W1;
  ushort_t* Bp = Bp1;
  int t = idx;
  if (t >= per) { t -= per; W = W2; Bp = Bp2; }
  int j  = t & 7;
  int n  = (t >> 3) % KPAD;
  int kg = ((t >> 3) / KPAD) % 40;
  int i  = t / (40 * KPAD * 8);
  int k  = kg * 8 + j;
  float v = (k < H_ && n < H_) ? W[(i * H_ + k) * H_ + n] : 0.f;
  Bp[t] = f2b(v);
}

// h = relu(x @ W_pn + b_pn)
__global__ void proj_nodes(const float* __restrict__ x, const float* __restrict__ Wpn,
                           const float* __restrict__ bpn, float* __restrict__ h) {
  unsigned f = blockIdx.x * 256u + threadIdx.x;
  if (f >= (unsigned)N_NODES * H_) return;
  unsigned n = f / H_, hh = f % H_;
  float acc = bpn[hh];
  const float* xr = x + n * DIN_;
  const float* wc = Wpn + hh;
#pragma unroll 8
  for (int k = 0; k < DIN_; ++k) acc += xr[k] * wc[k * H_];
  h[f] = fmaxf(acc, 0.f);
}

// agg[dst] += relu(h[src] + (edge_attr @ W_pe + b_pe))   (e recomputed on the fly)
__global__ void edge_agg(const float* __restrict__ h, const float* __restrict__ ea,
                         const float* __restrict__ Wpe, const float* __restrict__ bpe,
                         const int* __restrict__ src, const int* __restrict__ dst,
                         float* __restrict__ agg) {
  unsigned f = blockIdx.x * 256u + threadIdx.x;
  if (f >= (unsigned)N_EDGES * H_) return;
  unsigned e = f / H_, hh = f % H_;
  float acc = bpe[hh];
  const float* ar = ea + e * EIN_;
  const float* wc = Wpe + hh;
#pragma unroll
  for (int k = 0; k < EIN_; ++k) acc += ar[k] * wc[k * H_];
  float m = h[(unsigned)src[e] * H_ + hh] + acc;
  m = fmaxf(m, 0.f);
  atomicAdd(agg + (unsigned)dst[e] * H_ + hh, m);
}

// zb = bf16(h + agg), zero-padded to [NPAD][320]
__global__ void zprep(const float* __restrict__ h, const float* __restrict__ agg,
                      ushort_t* __restrict__ zb) {
  unsigned f = blockIdx.x * 256u + threadIdx.x;
  if (f >= (unsigned)NPAD * KPAD) return;
  unsigned n = f / KPAD, c = f % KPAD;
  float v = 0.f;
  if (n < N_NODES && c < H_) v = h[n * H_ + c] + agg[n * H_ + c];
  zb[f] = f2b(v);
}

// C = act(A @ W + bias).  A: bf16 [NPAD][320].  Bp: frag-packed bf16 [40][320][8].
// OUT_BF16: write bf16 [NPAD][320] (pad cols = 0); else fp32 [N][300].
template <int RELU_OUT, int OUT_BF16>
__global__ __launch_bounds__(256) void gemm300(const ushort_t* __restrict__ A,
                                               const ushort_t* __restrict__ Bp,
                                               const float* __restrict__ bias,
                                               void* __restrict__ Cout) {
  int lane = threadIdx.x & 63;
  int wid  = threadIdx.x >> 6;
  int lr = lane & 15, lg = lane >> 4;
  int rowblk  = blockIdx.x * 64 + (wid & 1) * 32;  // wave: 32 rows x 160 cols
  int colbase = (wid >> 1) * 160;
  f32x4 acc[2][10];
#pragma unroll
  for (int a = 0; a < 2; ++a)
#pragma unroll
    for (int c = 0; c < 10; ++c) acc[a][c] = (f32x4){0.f, 0.f, 0.f, 0.f};

  const ushort_t* Ap = A + (unsigned)(rowblk + lr) * KPAD + lg * 8;
  for (int k0 = 0; k0 < KPAD; k0 += 32) {
    bf16x8 a0 = *(const bf16x8*)(Ap + k0);
    bf16x8 a1 = *(const bf16x8*)(Ap + 16 * KPAD + k0);
    const ushort_t* bb = Bp + ((unsigned)(k0 / 8 + lg) * KPAD + colbase + lr) * 8;
#pragma unroll
    for (int c = 0; c < 10; ++c) {
      bf16x8 b = *(const bf16x8*)(bb + c * 16 * 8);
      acc[0][c] = __builtin_amdgcn_mfma_f32_16x16x32_bf16(a0, b, acc[0][c], 0, 0, 0);
      acc[1][c] = __builtin_amdgcn_mfma_f32_16x16x32_bf16(a1, b, acc[1][c], 0, 0, 0);
    }
  }
  // epilogue: D mapping col=lane&15, row=(lane>>4)*4+r  [m89/m91]
#pragma unroll
  for (int rt = 0; rt < 2; ++rt) {
#pragma unroll
    for (int c = 0; c < 10; ++c) {
      int col = colbase + c * 16 + lr;
      float bv = (col < H_) ? bias[col] : 0.f;
#pragma unroll
      for (int r = 0; r < 4; ++r) {
        int row = rowblk + rt * 16 + lg * 4 + r;
        if (row >= N_NODES) continue;
        float v = acc[rt][c][r] + bv;
        if (RELU_OUT) v = fmaxf(v, 0.f);
        if (OUT_BF16) {
          ((ushort_t*)Cout)[(unsigned)row * KPAD + col] = f2b(v);
        } else if (col < H_) {
          ((float*)Cout)[(unsigned)row * H_ + col] = v;
        }
      }
    }
  }
}

// pooled[g] = sum of h rows with batch==g (batch sorted -> binary search bounds)
__global__ void pool_kernel(const float* __restrict__ h, const int* __restrict__ batch,
                            float* __restrict__ pooled) {
  int g = blockIdx.x;
  int hh = threadIdx.x;  // block 320
  int lo = 0, hi = N_NODES;
  while (lo < hi) { int mid = (lo + hi) >> 1; if (batch[mid] < g) lo = mid + 1; else hi = mid; }
  int start = lo;
  hi = N_NODES;
  while (lo < hi) { int mid = (lo + hi) >> 1; if (batch[mid] < g + 1) lo = mid + 1; else hi = mid; }
  int end = lo;
  if (hh >= H_) return;
  float s = 0.f;
  for (int n = start; n < end; ++n) s += h[(unsigned)n * H_ + hh];
  pooled[g * H_ + hh] = s;
}

// out = prelu(pooled @ W_sp + b_sp)
__global__ void final_kernel(const float* __restrict__ pooled, const float* __restrict__ Wsp,
                             const float* __restrict__ bsp, const float* __restrict__ pa,
                             float* __restrict__ out) {
  int f = blockIdx.x * 256 + threadIdx.x;
  if (f >= G_GR * R_OUT) return;
  int g = f >> 10, r = f & 1023;
  float acc = bsp[r];
  const float* pr = pooled + g * H_;
  const float* wc = Wsp + r;
  for (int k = 0; k < H_; ++k) acc += pr[k] * wc[k * R_OUT];
  float a = pa[0];
  out[f] = acc >= 0.f ? acc : a * acc;
}

extern "C" void kernel_launch(void* const* d_in, const int* in_sizes, int n_in,
                              void* d_out, int out_size, void* d_ws, size_t ws_size,
                              hipStream_t stream) {
  const float* x   = (const float*)d_in[0];
  const float* ea  = (const float*)d_in[1];
  const int*   ei  = (const int*)d_in[2];
  const int*   bat = (const int*)d_in[3];
  const float* Wpn = (const float*)d_in[4];
  const float* bpn = (const float*)d_in[5];
  const float* Wpe = (const float*)d_in[6];
  const float* bpe = (const float*)d_in[7];
  const float* W1  = (const float*)d_in[8];
  const float* b1  = (const float*)d_in[9];
  const float* W2  = (const float*)d_in[10];
  const float* b2  = (const float*)d_in[11];
  const float* Wsp = (const float*)d_in[12];
  const float* bsp = (const float*)d_in[13];
  const float* pa  = (const float*)d_in[14];
  const int* src = ei;
  const int* dst = ei + N_EDGES;

  char* ws = (char*)d_ws;
  size_t off = 0;
  auto alloc = [&](size_t bytes) {
    void* p = ws + off;
    off += (bytes + 255) & ~(size_t)255;
    return p;
  };
  float*    h      = (float*)alloc(sizeof(float) * (size_t)N_NODES * H_);
  float*    agg    = (float*)alloc(sizeof(float) * (size_t)N_NODES * H_);
  ushort_t* zb     = (ushort_t*)alloc(sizeof(ushort_t) * (size_t)NPAD * KPAD);
  ushort_t* tb     = (ushort_t*)alloc(sizeof(ushort_t) * (size_t)NPAD * KPAD);
  ushort_t* Bp1    = (ushort_t*)alloc(sizeof(ushort_t) * (size_t)DEPTH_ * 40 * KPAD * 8);
  ushort_t* Bp2    = (ushort_t*)alloc(sizeof(ushort_t) * (size_t)DEPTH_ * 40 * KPAD * 8);
  float*    pooled = (float*)alloc(sizeof(float) * (size_t)G_GR * H_);

  pack_weights<<<(2 * DEPTH_ * 40 * KPAD * 8 + 255) / 256, 256, 0, stream>>>(W1, W2, Bp1, Bp2);
  proj_nodes<<<((unsigned)N_NODES * H_ + 255) / 256, 256, 0, stream>>>(x, Wpn, bpn, h);

  for (int i = 0; i < DEPTH_; ++i) {
    hipMemsetAsync(agg, 0, sizeof(float) * (size_t)N_NODES * H_, stream);
    edge_agg<<<((unsigned)N_EDGES * H_ + 255) / 256, 256, 0, stream>>>(h, ea, Wpe, bpe, src, dst, agg);
    zprep<<<((unsigned)NPAD * KPAD + 255) / 256, 256, 0, stream>>>(h, agg, zb);
    gemm300<1, 1><<<NPAD / 64, 256, 0, stream>>>(zb, Bp1 + (size_t)i * 40 * KPAD * 8, b1 + i * H_, tb);
    if (i < DEPTH_ - 1)
      gemm300<1, 0><<<NPAD / 64, 256, 0, stream>>>(tb, Bp2 + (size_t)i * 40 * KPAD * 8, b2 + i * H_, h);
    else
      gemm300<0, 0><<<NPAD / 64, 256, 0, stream>>>(tb, Bp2 + (size_t)i * 40 * KPAD * 8, b2 + i * H_, h);
  }

  pool_kernel<<<G_GR, 320, 0, stream>>>(h, bat, pooled);
  final_kernel<<<(G_GR * R_OUT) / 256, 256, 0, stream>>>(pooled, Wsp, bsp, pa, (float*)d_out);
}

// Round 2
// 2744.945 us; speedup vs baseline: 2.4335x; 2.4335x over previous
//
#include <hip/hip_runtime.h>
#include <hip/hip_bf16.h>

#define N_NODES 50000
#define N_EDGES 800000
#define DIN_    64
#define EIN_    16
#define H_      300
#define R_OUT   1024
#define G_GR    256
#define DEPTH_  5
#define KPAD    320
#define NPAD    50048   // multiple of 64 >= N_NODES

typedef unsigned short ushort_t;
typedef __attribute__((ext_vector_type(8))) short bf16x8;
typedef __attribute__((ext_vector_type(4))) float f32x4;

__device__ __forceinline__ ushort_t f2b(float f) {
  unsigned x = __float_as_uint(f);
  unsigned r = (x + 0x7fffu + ((x >> 16) & 1u)) >> 16;  // RTN-even
  return (ushort_t)r;
}

// ---------------- weight packing (once per call) ----------------
// Pack W1/W2 (fp32 [DEPTH][300][300], k-major) into bf16 frag layout
// Bp[i][kg][n][j] , k = kg*8+j, zero-padded to 320x320.
__global__ void pack_weights(const float* __restrict__ W1, const float* __restrict__ W2,
                             ushort_t* __restrict__ Bp1, ushort_t* __restrict__ Bp2) {
  int idx = blockIdx.x * 256 + threadIdx.x;
  const int per = DEPTH_ * 40 * KPAD * 8;  // 512000
  if (idx >= 2 * per) return;
  const float* W = W1;
  ushort_t* Bp = Bp1;
  int t = idx;
  if (t >= per) { t -= per; W = W2; Bp = Bp2; }
  int j  = t & 7;
  int n  = (t >> 3) % KPAD;
  int kg = ((t >> 3) / KPAD) % 40;
  int i  = t / (40 * KPAD * 8);
  int k  = kg * 8 + j;
  float v = (k < H_ && n < H_) ? W[(i * H_ + k) * H_ + n] : 0.f;
  Bp[t] = f2b(v);
}

// ---------------- CSR build (once per call) ----------------
__global__ void hist_deg(const int* __restrict__ dst, int* __restrict__ deg) {
  int e = blockIdx.x * 256 + threadIdx.x;
  if (e < N_EDGES) atomicAdd(deg + dst[e], 1);
}

// single-block exclusive scan of deg[0..N_NODES) -> off, off[N_NODES]=total
__global__ __launch_bounds__(1024) void exscan_kernel(const int* __restrict__ deg,
                                                      int* __restrict__ off) {
  __shared__ int wsum[16];
  __shared__ int carry_s;
  int lane = threadIdx.x & 63;
  int wv = threadIdx.x >> 6;
  if (threadIdx.x == 0) carry_s = 0;
  __syncthreads();
  for (int base = 0; base < N_NODES; base += 1024) {
    int i = base + (int)threadIdx.x;
    int orig = (i < N_NODES) ? deg[i] : 0;
    int v = orig;
#pragma unroll
    for (int s = 1; s < 64; s <<= 1) {
      int u = __shfl_up(v, s);
      if (lane >= s) v += u;
    }
    if (lane == 63) wsum[wv] = v;
    __syncthreads();
    if (wv == 0) {
      int t = (lane < 16) ? wsum[lane] : 0;
#pragma unroll
      for (int s = 1; s < 16; s <<= 1) {
        int u = __shfl_up(t, s);
        if (lane >= s) t += u;
      }
      if (lane < 16) wsum[lane] = t;
    }
    __syncthreads();
    int wbase = (wv > 0) ? wsum[wv - 1] : 0;
    if (i < N_NODES) off[i] = carry_s + wbase + v - orig;
    __syncthreads();
    if (threadIdx.x == 1023) carry_s += wsum[15];
    __syncthreads();
  }
  if (threadIdx.x == 0) off[N_NODES] = carry_s;
}

__global__ void scatter_edges(const int* __restrict__ src, const int* __restrict__ dst,
                              int* __restrict__ cursor, int* __restrict__ csr_src,
                              int* __restrict__ csr_eid) {
  int e = blockIdx.x * 256 + threadIdx.x;
  if (e >= N_EDGES) return;
  int d = dst[e];
  int pos = atomicAdd(cursor + d, 1);
  csr_src[pos] = src[e];
  csr_eid[pos] = e;
}

// ---------------- per-layer kernels ----------------
// h = relu(x @ W_pn + b_pn)
__global__ void proj_nodes(const float* __restrict__ x, const float* __restrict__ Wpn,
                           const float* __restrict__ bpn, float* __restrict__ h) {
  unsigned f = blockIdx.x * 256u + threadIdx.x;
  if (f >= (unsigned)N_NODES * H_) return;
  unsigned n = f / H_, hh = f % H_;
  float acc = bpn[hh];
  const float* xr = x + n * DIN_;
  const float* wc = Wpn + hh;
#pragma unroll 8
  for (int k = 0; k < DIN_; ++k) acc += xr[k] * wc[k * H_];
  h[f] = fmaxf(acc, 0.f);
}

// zb[n][t] = bf16( h[n][t] + sum_{e in CSR(n)} relu(h[src_e][t] + (ea[e]@Wpe+bpe)[t]) )
// grid = NPAD blocks x 320 threads; pad rows/cols written as zero.
__global__ __launch_bounds__(320) void node_agg(const float* __restrict__ h,
                                                const float* __restrict__ ea,
                                                const float* __restrict__ Wpe,
                                                const float* __restrict__ bpe,
                                                const int* __restrict__ csr_src,
                                                const int* __restrict__ csr_eid,
                                                const int* __restrict__ off,
                                                ushort_t* __restrict__ zb) {
  int n = blockIdx.x;
  int t = threadIdx.x;  // 0..319
  if (n >= N_NODES || t >= H_) {
    zb[(unsigned)n * KPAD + t] = 0;
    return;
  }
  int p0 = off[n], p1 = off[n + 1];
  float acc = h[(unsigned)n * H_ + t];
  float w[EIN_];
#pragma unroll
  for (int k = 0; k < EIN_; ++k) w[k] = Wpe[k * H_ + t];
  float bb = bpe[t];
  for (int p = p0; p < p1; ++p) {
    int sn = csr_src[p];
    int eid = csr_eid[p];
    float m = bb + h[(unsigned)sn * H_ + t];
    const float* ar = ea + (unsigned)eid * EIN_;
#pragma unroll
    for (int k = 0; k < EIN_; ++k) m += ar[k] * w[k];
    acc += fmaxf(m, 0.f);
  }
  zb[(unsigned)n * KPAD + t] = f2b(acc);
}

// C = act(A @ W + bias).  A: bf16 [NPAD][320].  Bp: frag-packed bf16 [40][320][8].
// OUT_BF16: write bf16 [NPAD][320] (pad cols = 0); else fp32 [N][300].
template <int RELU_OUT, int OUT_BF16>
__global__ __launch_bounds__(256) void gemm300(const ushort_t* __restrict__ A,
                                               const ushort_t* __restrict__ Bp,
                                               const float* __restrict__ bias,
                                               void* __restrict__ Cout) {
  int lane = threadIdx.x & 63;
  int wid  = threadIdx.x >> 6;
  int lr = lane & 15, lg = lane >> 4;
  int rowblk  = blockIdx.x * 64 + (wid & 1) * 32;  // wave: 32 rows x 160 cols
  int colbase = (wid >> 1) * 160;
  f32x4 acc[2][10];
#pragma unroll
  for (int a = 0; a < 2; ++a)
#pragma unroll
    for (int c = 0; c < 10; ++c) acc[a][c] = (f32x4){0.f, 0.f, 0.f, 0.f};

  const ushort_t* Ap = A + (unsigned)(rowblk + lr) * KPAD + lg * 8;
  for (int k0 = 0; k0 < KPAD; k0 += 32) {
    bf16x8 a0 = *(const bf16x8*)(Ap + k0);
    bf16x8 a1 = *(const bf16x8*)(Ap + 16 * KPAD + k0);
    const ushort_t* bb = Bp + ((unsigned)(k0 / 8 + lg) * KPAD + colbase + lr) * 8;
#pragma unroll
    for (int c = 0; c < 10; ++c) {
      bf16x8 b = *(const bf16x8*)(bb + c * 16 * 8);
      acc[0][c] = __builtin_amdgcn_mfma_f32_16x16x32_bf16(a0, b, acc[0][c], 0, 0, 0);
      acc[1][c] = __builtin_amdgcn_mfma_f32_16x16x32_bf16(a1, b, acc[1][c], 0, 0, 0);
    }
  }
  // epilogue: D mapping col=lane&15, row=(lane>>4)*4+r  [m89/m91]
#pragma unroll
  for (int rt = 0; rt < 2; ++rt) {
#pragma unroll
    for (int c = 0; c < 10; ++c) {
      int col = colbase + c * 16 + lr;
      float bv = (col < H_) ? bias[col] : 0.f;
#pragma unroll
      for (int r = 0; r < 4; ++r) {
        int row = rowblk + rt * 16 + lg * 4 + r;
        if (row >= N_NODES) continue;
        float v = acc[rt][c][r] + bv;
        if (RELU_OUT) v = fmaxf(v, 0.f);
        if (OUT_BF16) {
          ((ushort_t*)Cout)[(unsigned)row * KPAD + col] = f2b(v);
        } else if (col < H_) {
          ((float*)Cout)[(unsigned)row * H_ + col] = v;
        }
      }
    }
  }
}

// pooled[g] = sum of h rows with batch==g (batch sorted -> binary search bounds)
__global__ void pool_kernel(const float* __restrict__ h, const int* __restrict__ batch,
                            float* __restrict__ pooled) {
  int g = blockIdx.x;
  int hh = threadIdx.x;  // block 320
  int lo = 0, hi = N_NODES;
  while (lo < hi) { int mid = (lo + hi) >> 1; if (batch[mid] < g) lo = mid + 1; else hi = mid; }
  int start = lo;
  hi = N_NODES;
  while (lo < hi) { int mid = (lo + hi) >> 1; if (batch[mid] < g + 1) lo = mid + 1; else hi = mid; }
  int end = lo;
  if (hh >= H_) return;
  float s = 0.f;
  for (int n = start; n < end; ++n) s += h[(unsigned)n * H_ + hh];
  pooled[g * H_ + hh] = s;
}

// out = prelu(pooled @ W_sp + b_sp)
__global__ void final_kernel(const float* __restrict__ pooled, const float* __restrict__ Wsp,
                             const float* __restrict__ bsp, const float* __restrict__ pa,
                             float* __restrict__ out) {
  int f = blockIdx.x * 256 + threadIdx.x;
  if (f >= G_GR * R_OUT) return;
  int g = f >> 10, r = f & 1023;
  float acc = bsp[r];
  const float* pr = pooled + g * H_;
  const float* wc = Wsp + r;
  for (int k = 0; k < H_; ++k) acc += pr[k] * wc[k * R_OUT];
  float a = pa[0];
  out[f] = acc >= 0.f ? acc : a * acc;
}

extern "C" void kernel_launch(void* const* d_in, const int* in_sizes, int n_in,
                              void* d_out, int out_size, void* d_ws, size_t ws_size,
                              hipStream_t stream) {
  const float* x   = (const float*)d_in[0];
  const float* ea  = (const float*)d_in[1];
  const int*   ei  = (const int*)d_in[2];
  const int*   bat = (const int*)d_in[3];
  const float* Wpn = (const float*)d_in[4];
  const float* bpn = (const float*)d_in[5];
  const float* Wpe = (const float*)d_in[6];
  const float* bpe = (const float*)d_in[7];
  const float* W1  = (const float*)d_in[8];
  const float* b1  = (const float*)d_in[9];
  const float* W2  = (const float*)d_in[10];
  const float* b2  = (const float*)d_in[11];
  const float* Wsp = (const float*)d_in[12];
  const float* bsp = (const float*)d_in[13];
  const float* pa  = (const float*)d_in[14];
  const int* src = ei;
  const int* dst = ei + N_EDGES;

  char* ws = (char*)d_ws;
  size_t off_b = 0;
  auto alloc = [&](size_t bytes) {
    void* p = ws + off_b;
    off_b += (bytes + 255) & ~(size_t)255;
    return p;
  };
  float*    h       = (float*)alloc(sizeof(float) * (size_t)N_NODES * H_);
  ushort_t* zb      = (ushort_t*)alloc(sizeof(ushort_t) * (size_t)NPAD * KPAD);
  ushort_t* tb      = (ushort_t*)alloc(sizeof(ushort_t) * (size_t)NPAD * KPAD);
  ushort_t* Bp1     = (ushort_t*)alloc(sizeof(ushort_t) * (size_t)DEPTH_ * 40 * KPAD * 8);
  ushort_t* Bp2     = (ushort_t*)alloc(sizeof(ushort_t) * (size_t)DEPTH_ * 40 * KPAD * 8);
  float*    pooled  = (float*)alloc(sizeof(float) * (size_t)G_GR * H_);
  int*      deg     = (int*)alloc(sizeof(int) * N_NODES);
  int*      offs    = (int*)alloc(sizeof(int) * (N_NODES + 1));
  int*      cursor  = (int*)alloc(sizeof(int) * N_NODES);
  int*      csr_src = (int*)alloc(sizeof(int) * N_EDGES);
  int*      csr_eid = (int*)alloc(sizeof(int) * N_EDGES);

  // ---- CSR build ----
  hipMemsetAsync(deg, 0, sizeof(int) * N_NODES, stream);
  hist_deg<<<(N_EDGES + 255) / 256, 256, 0, stream>>>(dst, deg);
  exscan_kernel<<<1, 1024, 0, stream>>>(deg, offs);
  hipMemcpyAsync(cursor, offs, sizeof(int) * N_NODES, hipMemcpyDeviceToDevice, stream);
  scatter_edges<<<(N_EDGES + 255) / 256, 256, 0, stream>>>(src, dst, cursor, csr_src, csr_eid);

  pack_weights<<<(2 * DEPTH_ * 40 * KPAD * 8 + 255) / 256, 256, 0, stream>>>(W1, W2, Bp1, Bp2);
  proj_nodes<<<((unsigned)N_NODES * H_ + 255) / 256, 256, 0, stream>>>(x, Wpn, bpn, h);

  for (int i = 0; i < DEPTH_; ++i) {
    node_agg<<<NPAD, 320, 0, stream>>>(h, ea, Wpe, bpe, csr_src, csr_eid, offs, zb);
    gemm300<1, 1><<<NPAD / 64, 256, 0, stream>>>(zb, Bp1 + (size_t)i * 40 * KPAD * 8, b1 + i * H_, tb);
    if (i < DEPTH_ - 1)
      gemm300<1, 0><<<NPAD / 64, 256, 0, stream>>>(tb, Bp2 + (size_t)i * 40 * KPAD * 8, b2 + i * H_, h);
    else
      gemm300<0, 0><<<NPAD / 64, 256, 0, stream>>>(tb, Bp2 + (size_t)i * 40 * KPAD * 8, b2 + i * H_, h);
  }

  pool_kernel<<<G_GR, 320, 0, stream>>>(h, bat, pooled);
  final_kernel<<<(G_GR * R_OUT) / 256, 256, 0, stream>>>(pooled, Wsp, bsp, pa, (float*)d_out);
}

// Round 3
// 2348.880 us; speedup vs baseline: 2.8438x; 1.1686x over previous
//
#include <hip/hip_runtime.h>
#include <hip/hip_bf16.h>

#define N_NODES 50000
#define N_EDGES 800000
#define DIN_    64
#define EIN_    16
#define H_      300
#define R_OUT   1024
#define G_GR    256
#define DEPTH_  5
#define KPAD    320
#define NPAD    50048   // multiple of 64 >= N_NODES

typedef unsigned short ushort_t;
typedef __attribute__((ext_vector_type(8))) short bf16x8;
typedef __attribute__((ext_vector_type(4))) float f32x4;

__device__ __forceinline__ ushort_t f2b(float f) {
  unsigned x = __float_as_uint(f);
  unsigned r = (x + 0x7fffu + ((x >> 16) & 1u)) >> 16;  // RTN-even
  return (ushort_t)r;
}
__device__ __forceinline__ float b2f(ushort_t u) {
  return __uint_as_float((unsigned)u << 16);
}

// ---------------- weight packing (once per call) ----------------
// Pack W1/W2 (fp32 [DEPTH][300][300], k-major) into bf16 frag layout
// Bp[i][kg][n][j] , k = kg*8+j, zero-padded to 320x320.
__global__ void pack_weights(const float* __restrict__ W1, const float* __restrict__ W2,
                             ushort_t* __restrict__ Bp1, ushort_t* __restrict__ Bp2) {
  int idx = blockIdx.x * 256 + threadIdx.x;
  const int per = DEPTH_ * 40 * KPAD * 8;  // 512000
  if (idx >= 2 * per) return;
  const float* W = W1;
  ushort_t* Bp = Bp1;
  int t = idx;
  if (t >= per) { t -= per; W = W2; Bp = Bp2; }
  int j  = t & 7;
  int n  = (t >> 3) % KPAD;
  int kg = ((t >> 3) / KPAD) % 40;
  int i  = t / (40 * KPAD * 8);
  int k  = kg * 8 + j;
  float v = (k < H_ && n < H_) ? W[(i * H_ + k) * H_ + n] : 0.f;
  Bp[t] = f2b(v);
}

// ---------------- CSR build (once per call) ----------------
__global__ void hist_deg(const int* __restrict__ dst, int* __restrict__ deg) {
  int e = blockIdx.x * 256 + threadIdx.x;
  if (e < N_EDGES) atomicAdd(deg + dst[e], 1);
}

// single-block exclusive scan of deg[0..N_NODES) -> off, off[N_NODES]=total
__global__ __launch_bounds__(1024) void exscan_kernel(const int* __restrict__ deg,
                                                      int* __restrict__ off) {
  __shared__ int wsum[16];
  __shared__ int carry_s;
  int lane = threadIdx.x & 63;
  int wv = threadIdx.x >> 6;
  if (threadIdx.x == 0) carry_s = 0;
  __syncthreads();
  for (int base = 0; base < N_NODES; base += 1024) {
    int i = base + (int)threadIdx.x;
    int orig = (i < N_NODES) ? deg[i] : 0;
    int v = orig;
#pragma unroll
    for (int s = 1; s < 64; s <<= 1) {
      int u = __shfl_up(v, s);
      if (lane >= s) v += u;
    }
    if (lane == 63) wsum[wv] = v;
    __syncthreads();
    if (wv == 0) {
      int t = (lane < 16) ? wsum[lane] : 0;
#pragma unroll
      for (int s = 1; s < 16; s <<= 1) {
        int u = __shfl_up(t, s);
        if (lane >= s) t += u;
      }
      if (lane < 16) wsum[lane] = t;
    }
    __syncthreads();
    int wbase = (wv > 0) ? wsum[wv - 1] : 0;
    if (i < N_NODES) off[i] = carry_s + wbase + v - orig;
    __syncthreads();
    if (threadIdx.x == 1023) carry_s += wsum[15];
    __syncthreads();
  }
  if (threadIdx.x == 0) off[N_NODES] = carry_s;
}

__global__ void scatter_edges(const int* __restrict__ src, const int* __restrict__ dst,
                              int* __restrict__ cursor, int2* __restrict__ csr) {
  int e = blockIdx.x * 256 + threadIdx.x;
  if (e >= N_EDGES) return;
  int d = dst[e];
  int pos = atomicAdd(cursor + d, 1);
  csr[pos] = make_int2(src[e], e);
}

// ---------------- per-layer kernels ----------------
// hb = bf16(relu(x @ W_pn + b_pn)), zero-padded [NPAD][KPAD]
__global__ void proj_nodes(const float* __restrict__ x, const float* __restrict__ Wpn,
                           const float* __restrict__ bpn, ushort_t* __restrict__ hb) {
  unsigned f = blockIdx.x * 256u + threadIdx.x;
  if (f >= (unsigned)NPAD * KPAD) return;
  unsigned n = f / KPAD, hh = f % KPAD;
  float v = 0.f;
  if (n < N_NODES && hh < H_) {
    float acc = bpn[hh];
    const float* xr = x + n * DIN_;
    const float* wc = Wpn + hh;
#pragma unroll 8
    for (int k = 0; k < DIN_; ++k) acc += xr[k] * wc[k * H_];
    v = fmaxf(acc, 0.f);
  }
  hb[f] = f2b(v);
}

__device__ __forceinline__ float edot(const float* __restrict__ ar, const float* w) {
  f32x4 v0 = *(const f32x4*)ar;
  f32x4 v1 = *(const f32x4*)(ar + 4);
  f32x4 v2 = *(const f32x4*)(ar + 8);
  f32x4 v3 = *(const f32x4*)(ar + 12);
  float s = v0[0] * w[0] + v0[1] * w[1] + v0[2] * w[2] + v0[3] * w[3];
  s += v1[0] * w[4] + v1[1] * w[5] + v1[2] * w[6] + v1[3] * w[7];
  s += v2[0] * w[8] + v2[1] * w[9] + v2[2] * w[10] + v2[3] * w[11];
  s += v3[0] * w[12] + v3[1] * w[13] + v3[2] * w[14] + v3[3] * w[15];
  return s;
}

// zb[n][t] = bf16( hb[n][t] + sum_{e in CSR(n)} relu(hb[src_e][t] + (ea[e]@Wpe+bpe)[t]) )
// grid = NPAD blocks x 320 threads; pad rows/cols written as zero.
__global__ __launch_bounds__(320) void node_agg(const ushort_t* __restrict__ hb,
                                                const float* __restrict__ ea,
                                                const float* __restrict__ Wpe,
                                                const float* __restrict__ bpe,
                                                const int2* __restrict__ csr,
                                                const int* __restrict__ off,
                                                ushort_t* __restrict__ zb) {
  int n = blockIdx.x;
  int t = threadIdx.x;  // 0..319
  unsigned zi = (unsigned)n * KPAD + t;
  if (n >= N_NODES || t >= H_) {
    zb[zi] = 0;
    return;
  }
  int p0 = off[n], p1 = off[n + 1];
  float acc = b2f(hb[zi]);  // self term
  float w[EIN_];
#pragma unroll
  for (int k = 0; k < EIN_; ++k) w[k] = Wpe[k * H_ + t];
  float bb = bpe[t];
  int p = p0;
  // unroll-4: issue all gathers + ea loads up front for MLP
  for (; p + 4 <= p1; p += 4) {
    int2 se0 = csr[p], se1 = csr[p + 1], se2 = csr[p + 2], se3 = csr[p + 3];
    float g0 = b2f(hb[(unsigned)se0.x * KPAD + t]);
    float g1 = b2f(hb[(unsigned)se1.x * KPAD + t]);
    float g2 = b2f(hb[(unsigned)se2.x * KPAD + t]);
    float g3 = b2f(hb[(unsigned)se3.x * KPAD + t]);
    float d0 = edot(ea + (unsigned)se0.y * EIN_, w);
    float d1 = edot(ea + (unsigned)se1.y * EIN_, w);
    float d2 = edot(ea + (unsigned)se2.y * EIN_, w);
    float d3 = edot(ea + (unsigned)se3.y * EIN_, w);
    acc += fmaxf(g0 + d0 + bb, 0.f);
    acc += fmaxf(g1 + d1 + bb, 0.f);
    acc += fmaxf(g2 + d2 + bb, 0.f);
    acc += fmaxf(g3 + d3 + bb, 0.f);
  }
  for (; p < p1; ++p) {
    int2 se = csr[p];
    float g = b2f(hb[(unsigned)se.x * KPAD + t]);
    float d = edot(ea + (unsigned)se.y * EIN_, w);
    acc += fmaxf(g + d + bb, 0.f);
  }
  zb[zi] = f2b(acc);
}

// C = act(A @ W + bias).  A: bf16 [NPAD][320].  Bp: frag-packed bf16 [40][320][8].
// OUT_BF16: write bf16 [NPAD][320] (pad cols = 0); else fp32 [N][300].
template <int RELU_OUT, int OUT_BF16>
__global__ __launch_bounds__(256) void gemm300(const ushort_t* __restrict__ A,
                                               const ushort_t* __restrict__ Bp,
                                               const float* __restrict__ bias,
                                               void* __restrict__ Cout) {
  int lane = threadIdx.x & 63;
  int wid  = threadIdx.x >> 6;
  int lr = lane & 15, lg = lane >> 4;
  int rowblk  = blockIdx.x * 64 + (wid & 1) * 32;  // wave: 32 rows x 160 cols
  int colbase = (wid >> 1) * 160;
  f32x4 acc[2][10];
#pragma unroll
  for (int a = 0; a < 2; ++a)
#pragma unroll
    for (int c = 0; c < 10; ++c) acc[a][c] = (f32x4){0.f, 0.f, 0.f, 0.f};

  const ushort_t* Ap = A + (unsigned)(rowblk + lr) * KPAD + lg * 8;
  for (int k0 = 0; k0 < KPAD; k0 += 32) {
    bf16x8 a0 = *(const bf16x8*)(Ap + k0);
    bf16x8 a1 = *(const bf16x8*)(Ap + 16 * KPAD + k0);
    const ushort_t* bb = Bp + ((unsigned)(k0 / 8 + lg) * KPAD + colbase + lr) * 8;
#pragma unroll
    for (int c = 0; c < 10; ++c) {
      bf16x8 b = *(const bf16x8*)(bb + c * 16 * 8);
      acc[0][c] = __builtin_amdgcn_mfma_f32_16x16x32_bf16(a0, b, acc[0][c], 0, 0, 0);
      acc[1][c] = __builtin_amdgcn_mfma_f32_16x16x32_bf16(a1, b, acc[1][c], 0, 0, 0);
    }
  }
  // epilogue: D mapping col=lane&15, row=(lane>>4)*4+r  [m89/m91]
#pragma unroll
  for (int rt = 0; rt < 2; ++rt) {
#pragma unroll
    for (int c = 0; c < 10; ++c) {
      int col = colbase + c * 16 + lr;
      float bv = (col < H_) ? bias[col] : 0.f;
#pragma unroll
      for (int r = 0; r < 4; ++r) {
        int row = rowblk + rt * 16 + lg * 4 + r;
        if (row >= N_NODES) continue;
        float v = acc[rt][c][r] + bv;
        if (RELU_OUT) v = fmaxf(v, 0.f);
        if (OUT_BF16) {
          ((ushort_t*)Cout)[(unsigned)row * KPAD + col] = f2b(v);
        } else if (col < H_) {
          ((float*)Cout)[(unsigned)row * H_ + col] = v;
        }
      }
    }
  }
}

// pooled[g] = sum of h rows with batch==g (batch sorted -> binary search bounds)
__global__ void pool_kernel(const float* __restrict__ h, const int* __restrict__ batch,
                            float* __restrict__ pooled) {
  int g = blockIdx.x;
  int hh = threadIdx.x;  // block 320
  int lo = 0, hi = N_NODES;
  while (lo < hi) { int mid = (lo + hi) >> 1; if (batch[mid] < g) lo = mid + 1; else hi = mid; }
  int start = lo;
  hi = N_NODES;
  while (lo < hi) { int mid = (lo + hi) >> 1; if (batch[mid] < g + 1) lo = mid + 1; else hi = mid; }
  int end = lo;
  if (hh >= H_) return;
  float s = 0.f;
  for (int n = start; n < end; ++n) s += h[(unsigned)n * H_ + hh];
  pooled[g * H_ + hh] = s;
}

// out = prelu(pooled @ W_sp + b_sp)
__global__ void final_kernel(const float* __restrict__ pooled, const float* __restrict__ Wsp,
                             const float* __restrict__ bsp, const float* __restrict__ pa,
                             float* __restrict__ out) {
  int f = blockIdx.x * 256 + threadIdx.x;
  if (f >= G_GR * R_OUT) return;
  int g = f >> 10, r = f & 1023;
  float acc = bsp[r];
  const float* pr = pooled + g * H_;
  const float* wc = Wsp + r;
  for (int k = 0; k < H_; ++k) acc += pr[k] * wc[k * R_OUT];
  float a = pa[0];
  out[f] = acc >= 0.f ? acc : a * acc;
}

extern "C" void kernel_launch(void* const* d_in, const int* in_sizes, int n_in,
                              void* d_out, int out_size, void* d_ws, size_t ws_size,
                              hipStream_t stream) {
  const float* x   = (const float*)d_in[0];
  const float* ea  = (const float*)d_in[1];
  const int*   ei  = (const int*)d_in[2];
  const int*   bat = (const int*)d_in[3];
  const float* Wpn = (const float*)d_in[4];
  const float* bpn = (const float*)d_in[5];
  const float* Wpe = (const float*)d_in[6];
  const float* bpe = (const float*)d_in[7];
  const float* W1  = (const float*)d_in[8];
  const float* b1  = (const float*)d_in[9];
  const float* W2  = (const float*)d_in[10];
  const float* b2  = (const float*)d_in[11];
  const float* Wsp = (const float*)d_in[12];
  const float* bsp = (const float*)d_in[13];
  const float* pa  = (const float*)d_in[14];
  const int* src = ei;
  const int* dst = ei + N_EDGES;

  char* ws = (char*)d_ws;
  size_t off_b = 0;
  auto alloc = [&](size_t bytes) {
    void* p = ws + off_b;
    off_b += (bytes + 255) & ~(size_t)255;
    return p;
  };
  ushort_t* hb      = (ushort_t*)alloc(sizeof(ushort_t) * (size_t)NPAD * KPAD);
  ushort_t* zb      = (ushort_t*)alloc(sizeof(ushort_t) * (size_t)NPAD * KPAD);
  ushort_t* tb      = (ushort_t*)alloc(sizeof(ushort_t) * (size_t)NPAD * KPAD);
  float*    h       = (float*)alloc(sizeof(float) * (size_t)N_NODES * H_);
  ushort_t* Bp1     = (ushort_t*)alloc(sizeof(ushort_t) * (size_t)DEPTH_ * 40 * KPAD * 8);
  ushort_t* Bp2     = (ushort_t*)alloc(sizeof(ushort_t) * (size_t)DEPTH_ * 40 * KPAD * 8);
  float*    pooled  = (float*)alloc(sizeof(float) * (size_t)G_GR * H_);
  int*      deg     = (int*)alloc(sizeof(int) * N_NODES);
  int*      offs    = (int*)alloc(sizeof(int) * (N_NODES + 1));
  int*      cursor  = (int*)alloc(sizeof(int) * N_NODES);
  int2*     csr     = (int2*)alloc(sizeof(int2) * N_EDGES);

  // ---- CSR build ----
  hipMemsetAsync(deg, 0, sizeof(int) * N_NODES, stream);
  hist_deg<<<(N_EDGES + 255) / 256, 256, 0, stream>>>(dst, deg);
  exscan_kernel<<<1, 1024, 0, stream>>>(deg, offs);
  hipMemcpyAsync(cursor, offs, sizeof(int) * N_NODES, hipMemcpyDeviceToDevice, stream);
  scatter_edges<<<(N_EDGES + 255) / 256, 256, 0, stream>>>(src, dst, cursor, csr);

  pack_weights<<<(2 * DEPTH_ * 40 * KPAD * 8 + 255) / 256, 256, 0, stream>>>(W1, W2, Bp1, Bp2);
  proj_nodes<<<((unsigned)NPAD * KPAD + 255) / 256, 256, 0, stream>>>(x, Wpn, bpn, hb);

  for (int i = 0; i < DEPTH_; ++i) {
    node_agg<<<NPAD, 320, 0, stream>>>(hb, ea, Wpe, bpe, csr, offs, zb);
    gemm300<1, 1><<<NPAD / 64, 256, 0, stream>>>(zb, Bp1 + (size_t)i * 40 * KPAD * 8, b1 + i * H_, tb);
    if (i < DEPTH_ - 1)
      gemm300<1, 1><<<NPAD / 64, 256, 0, stream>>>(tb, Bp2 + (size_t)i * 40 * KPAD * 8, b2 + i * H_, hb);
    else
      gemm300<0, 0><<<NPAD / 64, 256, 0, stream>>>(tb, Bp2 + (size_t)i * 40 * KPAD * 8, b2 + i * H_, h);
  }

  pool_kernel<<<G_GR, 320, 0, stream>>>(h, bat, pooled);
  final_kernel<<<(G_GR * R_OUT) / 256, 256, 0, stream>>>(pooled, Wsp, bsp, pa, (float*)d_out);
}